// Round 7
// baseline (81.197 us; speedup 1.0000x reference)
//
#include <hip/hip_runtime.h>
#include <hip/hip_bf16.h>

#define NN 50000
#define DEG 16
#define EE (NN*DEG)
#define CHUNKS 3125   // NN/16

typedef unsigned int uint;
typedef __attribute__((ext_vector_type(8))) short bf16x8;
typedef __attribute__((ext_vector_type(4))) float f32x4;

__device__ inline unsigned short f2b(float f){
  return __bfloat16_as_ushort(__float2bfloat16(f));
}
__device__ inline float b2f(uint lo16){ return __uint_as_float(lo16 << 16); }
__device__ inline float bhi(uint v){ return __uint_as_float(v & 0xffff0000u); }

// K1: bf16 MFMA GEMM. Per wave: 16 rows x 64 cols over K=128.
// Writes: interleaved bf16 gather table hev[r][128] = hv(64) | ev(64), fp32 s1/s2 scalars.
__global__ __launch_bounds__(256) void gemm_mfma_kernel(
    const float* __restrict__ in0, const float* __restrict__ in1,
    const float* __restrict__ W0,  const float* __restrict__ W1,
    const float* __restrict__ a0,  const float* __restrict__ a1,
    unsigned short* __restrict__ hev,
    float* __restrict__ s1ne, float* __restrict__ s2ne)
{
  const int pass = blockIdx.y;
  const float* in   = pass ? in1 : in0;
  const float* W    = pass ? W1  : W0;
  const float* av   = pass ? a1  : a0;

  // Stage W transposed (Wt[n][k], bf16) into LDS with 16B-block XOR swizzle.
  __shared__ unsigned short Wt[64*128];  // 16 KB
  const int tid = threadIdx.x;
  for (int b = tid; b < 1024; b += 256) {
    const int n  = b >> 4;          // 0..63
    const int k0 = (b & 15) * 8;    // 0..120
    uint4 pk;
    unsigned short* ps = (unsigned short*)&pk;
    #pragma unroll
    for (int j = 0; j < 8; j++) ps[j] = f2b(W[(k0 + j)*64 + n]);
    const int byte = n*256 + ((k0*2) ^ ((n & 7) << 4));
    *(uint4*)((char*)Wt + byte) = pk;
  }
  __syncthreads();

  const int wv   = tid >> 6;
  const int lane = tid & 63;
  const int g    = lane >> 4;     // k-group (0..3)
  const int c    = lane & 15;     // col/row low index

  // Hoist all 16 B-fragments (whole W) into VGPRs.
  bf16x8 wfrag[4][4];             // [ktile][ntile]
  #pragma unroll
  for (int kt = 0; kt < 4; kt++) {
    #pragma unroll
    for (int nt = 0; nt < 4; nt++) {
      const int n  = nt*16 + c;
      const int kb = (kt*32 + g*8) * 2;
      const int byte = n*256 + (kb ^ ((n & 7) << 4));
      wfrag[kt][nt] = *(bf16x8*)((char*)Wt + byte);
    }
  }
  float a1r[4], a2r[4];
  #pragma unroll
  for (int t = 0; t < 4; t++) { a1r[t] = av[t*16 + c]; a2r[t] = av[64 + t*16 + c]; }

  for (int ch = blockIdx.x*4 + wv; ch < CHUNKS; ch += gridDim.x*4) {
    const int r0 = ch * 16;
    const float* rowp = in + (long)(r0 + c)*128 + g*8;
    float4 ald[8];
    #pragma unroll
    for (int kt = 0; kt < 4; kt++) {
      ald[kt*2]   = *(const float4*)(rowp + kt*32);
      ald[kt*2+1] = *(const float4*)(rowp + kt*32 + 4);
    }
    f32x4 acc[4];
    #pragma unroll
    for (int nt = 0; nt < 4; nt++) acc[nt] = (f32x4){0.f, 0.f, 0.f, 0.f};
    #pragma unroll
    for (int kt = 0; kt < 4; kt++) {
      const float4 u = ald[kt*2], w = ald[kt*2+1];
      bf16x8 af;
      af[0] = (short)f2b(u.x); af[1] = (short)f2b(u.y);
      af[2] = (short)f2b(u.z); af[3] = (short)f2b(u.w);
      af[4] = (short)f2b(w.x); af[5] = (short)f2b(w.y);
      af[6] = (short)f2b(w.z); af[7] = (short)f2b(w.w);
      #pragma unroll
      for (int nt = 0; nt < 4; nt++)
        acc[nt] = __builtin_amdgcn_mfma_f32_16x16x32_bf16(af, wfrag[kt][nt], acc[nt], 0, 0, 0);
    }
    // C/D layout: col = nt*16 + (lane&15), row = g*4 + reg
    float q1v[4], q2v[4];
    #pragma unroll
    for (int v = 0; v < 4; v++) {
      float t1 = 0.f, t2 = 0.f;
      #pragma unroll
      for (int nt = 0; nt < 4; nt++) {
        t1 = fmaf(acc[nt][v], a1r[nt], t1);
        t2 = fmaf(acc[nt][v], a2r[nt], t2);
      }
      #pragma unroll
      for (int off = 1; off < 16; off <<= 1) {
        t1 += __shfl_xor(t1, off);
        t2 += __shfl_xor(t2, off);
      }
      q1v[v] = t1; q2v[v] = t2;
    }
    if (c < 4) {
      const float sv1 = (c==0) ? q1v[0] : (c==1) ? q1v[1] : (c==2) ? q1v[2] : q1v[3];
      const float sv2 = (c==0) ? q2v[0] : (c==1) ? q2v[1] : (c==2) ? q2v[2] : q2v[3];
      const int r = r0 + g*4 + c;
      s1ne[(long)r*2 + pass] = sv1;
      s2ne[(long)r*2 + pass] = sv2;
    }
    #pragma unroll
    for (int nt = 0; nt < 4; nt++) {
      #pragma unroll
      for (int v = 0; v < 4; v++) {
        const long r = r0 + g*4 + v;
        hev[r*128 + pass*64 + nt*16 + c] = f2b(acc[nt][v]);
      }
    }
  }
}

// K2: one wave = 4 nodes (64 edges). Gather: each load instr fetches FOUR
// 256B rows (uint4/lane, 16 lanes per row) -> 16 loads/group. Weights via
// 2 shuffles + select. Per-node cross-lane combine: shfl_xor(16), (32).
__global__ __launch_bounds__(256) void attn_kernel(
    const uint* __restrict__ hev,   // [NN][64] uints = [NN][128] bf16 (hv | ev)
    const float2* __restrict__ s1ne, const float2* __restrict__ s2ne,
    const int* __restrict__ edges,
    float* __restrict__ outp, double* __restrict__ partials)
{
  const int tid  = threadIdx.x;
  const int wv   = tid >> 6;
  const int lane = tid & 63;
  const int j    = lane >> 4;      // sub-node 0..3
  const int cl   = lane & 15;      // 16-lane column-block index
  double a_qn = 0.0, a_qe = 0.0;
  float* node_out = outp;
  float* edge_out = outp + (long)NN*128;
  const int NG = NN/4;             // 12500 groups
  for (int grp = blockIdx.x*4 + wv; grp < NG; grp += gridDim.x*4) {
    const int i0 = grp*4;
    // per-lane edge: (node i0+j, slot lane&15)
    const int dst = edges[((long)i0*16 + lane)*2 + 1];
    const float2 s1v = s1ne[i0 + j];
    const float2 gsc = s2ne[dst];
    float xn = s1v.x + gsc.x;
    float xe = s1v.y + gsc.y;
    xn = xn > 0.f ? xn : 0.2f*xn;
    xe = xe > 0.f ? xe : 0.2f*xe;
    xn = fminf(fmaxf(xn, -2.f), 2.f);
    xe = fminf(fmaxf(xe, -2.f), 2.f);
    const float an = expf(xn);
    const float ae = expf(xe);
    // 16-lane-group softmax denominators (4 nodes in parallel)
    float sn = an, se = ae;
    #pragma unroll
    for (int off = 1; off < 16; off <<= 1) {
      sn += __shfl_xor(sn, off);
      se += __shfl_xor(se, off);
    }
    const float wn = an / sn;
    const float we = ae / se;
    // sum of squares across all 64 edges of the group
    float rq = wn*wn, re = we*we;
    #pragma unroll
    for (int off = 1; off < 64; off <<= 1) {
      rq += __shfl_xor(rq, off);
      re += __shfl_xor(re, off);
    }
    if (lane == 0) { a_qn += (double)rq; a_qe += (double)re; }

    // own-row first halves: lane covers node (lane>>4), uints 4*cl..4*cl+3
    {
      const uint4 ov = *(const uint4*)(hev + (long)(i0 + j)*64 + cl*4);
      float* ob = ((cl < 8) ? node_out : edge_out) + (long)(i0 + j)*128 + 8*(cl & 7);
      *(float4*)(ob)     = make_float4(b2f(ov.x & 0xffffu), bhi(ov.x),
                                       b2f(ov.y & 0xffffu), bhi(ov.y));
      *(float4*)(ob + 4) = make_float4(b2f(ov.z & 0xffffu), bhi(ov.z),
                                       b2f(ov.w & 0xffffu), bhi(ov.w));
    }

    // gather-accumulate, one node at a time
    #pragma unroll
    for (int t = 0; t < 4; t++) {
      float acc[8];
      #pragma unroll
      for (int u = 0; u < 8; u++) acc[u] = 0.f;
      #pragma unroll
      for (int m = 0; m < 4; m++) {
        const int sl    = t*16 + m*4 + j;       // edge (node t, slot m*4 + j)
        const int d     = __shfl(dst, sl);
        const float w2n = __shfl(wn, sl);
        const float w2e = __shfl(we, sl);
        const float wk  = (cl < 8) ? w2n : w2e;
        const uint4 v = *(const uint4*)(hev + (long)d*64 + cl*4);
        acc[0] = fmaf(wk, b2f(v.x & 0xffffu), acc[0]);
        acc[1] = fmaf(wk, bhi(v.x),           acc[1]);
        acc[2] = fmaf(wk, b2f(v.y & 0xffffu), acc[2]);
        acc[3] = fmaf(wk, bhi(v.y),           acc[3]);
        acc[4] = fmaf(wk, b2f(v.z & 0xffffu), acc[4]);
        acc[5] = fmaf(wk, bhi(v.z),           acc[5]);
        acc[6] = fmaf(wk, b2f(v.w & 0xffffu), acc[6]);
        acc[7] = fmaf(wk, bhi(v.w),           acc[7]);
      }
      #pragma unroll
      for (int u = 0; u < 8; u++) {
        acc[u] += __shfl_xor(acc[u], 16);
        acc[u] += __shfl_xor(acc[u], 32);
      }
      if (lane < 16) {
        float* base = ((cl < 8) ? node_out : edge_out)
                      + (long)(i0 + t)*128 + 64 + 8*(cl & 7);
        *(float4*)(base)     = make_float4(acc[0], acc[1], acc[2], acc[3]);
        *(float4*)(base + 4) = make_float4(acc[4], acc[5], acc[6], acc[7]);
      }
    }
  }
  __shared__ double red[4][2];
  if (lane == 0) { red[wv][0] = a_qn; red[wv][1] = a_qe; }
  __syncthreads();
  if (tid == 0) {
    double t0 = 0, t1 = 0;
    #pragma unroll
    for (int w = 0; w < 4; w++) { t0 += red[w][0]; t1 += red[w][1]; }
    double* p = partials + (long)blockIdx.x*2;
    p[0] = t0; p[1] = t1;
  }
}

// K3: reduce partials -> the two variance scalars (sum of weights is exactly N)
__global__ __launch_bounds__(256) void finalize_kernel(
    const double* __restrict__ partials, int nparts, float* __restrict__ outp)
{
  const int tid = threadIdx.x;
  double l0 = 0, l1 = 0;
  for (int b = tid; b < nparts; b += 256) {
    l0 += partials[b*2+0]; l1 += partials[b*2+1];
  }
  __shared__ double red[256][2];
  red[tid][0] = l0; red[tid][1] = l1;
  __syncthreads();
  for (int s = 128; s > 0; s >>= 1) {
    if (tid < s) {
      red[tid][0] += red[tid+s][0];
      red[tid][1] += red[tid+s][1];
    }
    __syncthreads();
  }
  if (tid == 0) {
    const double E = (double)EE;
    const double S = (double)NN;
    double varn = (red[0][0] - S*S/E) / (E - 1.0);
    double vare = (red[0][1] - S*S/E) / (E - 1.0);
    outp[(long)NN*256 + 0] = (float)varn;
    outp[(long)NN*256 + 1] = (float)vare;
  }
}

extern "C" void kernel_launch(void* const* d_in, const int* in_sizes, int n_in,
                              void* d_out, int out_size, void* d_ws, size_t ws_size,
                              hipStream_t stream)
{
  const float* node_fts = (const float*)d_in[0];
  const float* edge_fts = (const float*)d_in[1];
  const int*   edges    = (const int*)d_in[2];
  const float* W_node   = (const float*)d_in[3];
  const float* W_edge   = (const float*)d_in[4];
  const float* a_node   = (const float*)d_in[5];
  const float* a_edge   = (const float*)d_in[6];

  char* ws = (char*)d_ws;
  unsigned short* hev = (unsigned short*)(ws);          // 12.8 MB interleaved table
  float* s1ne = (float*)(ws + 12800000);
  float* s2ne = (float*)(ws + 13200000);
  double* partials = (double*)(ws + 13600000);
  float* outp = (float*)d_out;

  hipLaunchKernelGGL(gemm_mfma_kernel, dim3(782, 2), dim3(256), 0, stream,
                     node_fts, edge_fts, W_node, W_edge, a_node, a_edge,
                     hev, s1ne, s2ne);
  const int AB = 3125;
  hipLaunchKernelGGL(attn_kernel, dim3(AB), dim3(256), 0, stream,
                     (const uint*)hev,
                     (const float2*)s1ne, (const float2*)s2ne,
                     edges, outp, partials);
  hipLaunchKernelGGL(finalize_kernel, dim3(1), dim3(256), 0, stream,
                     partials, AB, outp);
}

// Round 8
// 66.183 us; speedup vs baseline: 1.2269x; 1.2269x over previous
//
#include <hip/hip_runtime.h>
#include <hip/hip_bf16.h>

#define NN 50000
#define DEG 16
#define EE (NN*DEG)
#define CHUNKS 3125   // NN/16

typedef unsigned int uint;
typedef unsigned short ushort;
typedef __attribute__((ext_vector_type(8))) short bf16x8;
typedef __attribute__((ext_vector_type(4))) float f32x4;

__device__ inline ushort f2b(float f){
  return __bfloat16_as_ushort(__float2bfloat16(f));
}
__device__ inline float b2f(uint lo16){ return __uint_as_float(lo16 << 16); }
__device__ inline float bhi(uint v){ return __uint_as_float(v & 0xffff0000u); }

// K0: convert W (128x64 fp32) into MFMA A-operand fragment order, once.
// wf[pass][f=kt*4+nt][lane] = 8 bf16: Wt[n = nt*16+(lane&15)][k = kt*32+(lane>>4)*8 + j]
__global__ __launch_bounds__(256) void prep_kernel(
    const float* __restrict__ W0, const float* __restrict__ W1,
    uint4* __restrict__ wf)
{
  const int pass = blockIdx.y;
  const float* W = pass ? W1 : W0;
  const int t    = threadIdx.x;
  const int f    = blockIdx.x*4 + (t >> 6);   // fragment 0..15
  const int lane = t & 63;
  const int kt = f >> 2, nt = f & 3;
  const int n  = nt*16 + (lane & 15);
  const int k0 = kt*32 + (lane >> 4)*8;
  uint4 pk;
  ushort* ps = (ushort*)&pk;
  #pragma unroll
  for (int j = 0; j < 8; j++) ps[j] = f2b(W[(k0 + j)*64 + n]);
  wf[(pass*16 + f)*64 + lane] = pk;
}

// K1: bf16 MFMA GEMM, no LDS, one 16-row chunk per wave.
// Operands SWAPPED: D = Wt_tile * input_tile -> lane (g,c) holds
// out[row r0+c][feature nt*16 + g*4 + v]  (C/D: col=lane&15, row=g*4+v).
__global__ __launch_bounds__(256) void gemm_mfma_kernel(
    const float* __restrict__ in0, const float* __restrict__ in1,
    const uint4* __restrict__ wf,
    const float* __restrict__ a0,  const float* __restrict__ a1,
    ushort* __restrict__ hev,
    float* __restrict__ s1ne, float* __restrict__ s2ne)
{
  const int pass = blockIdx.y;
  const float* in = pass ? in1 : in0;
  const float* av = pass ? a1  : a0;

  const int tid  = threadIdx.x;
  const int wv   = tid >> 6;
  const int lane = tid & 63;
  const int g    = lane >> 4;
  const int c    = lane & 15;

  const int ch = blockIdx.x*4 + wv;
  if (ch >= CHUNKS) return;
  const int r0 = ch * 16;

  // 16 coalesced fragment loads (L1-resident after first block per CU)
  bf16x8 wfrag[16];
  const uint4* wfp = wf + (long)pass*16*64 + lane;
  #pragma unroll
  for (int f = 0; f < 16; f++) {
    uint4 v = wfp[f*64];
    wfrag[f] = *(bf16x8*)&v;
  }
  // per-lane attention coefficients for features nt*16 + g*4 + v
  float a1r[4][4], a2r[4][4];
  #pragma unroll
  for (int nt = 0; nt < 4; nt++)
    #pragma unroll
    for (int v = 0; v < 4; v++) {
      a1r[nt][v] = av[nt*16 + g*4 + v];
      a2r[nt][v] = av[64 + nt*16 + g*4 + v];
    }

  // input rows (B operand): lane (g,c) covers row r0+c, k = g*8 + kt*32
  const float* rowp = in + (long)(r0 + c)*128 + g*8;
  float4 ald[8];
  #pragma unroll
  for (int kt = 0; kt < 4; kt++) {
    ald[kt*2]   = *(const float4*)(rowp + kt*32);
    ald[kt*2+1] = *(const float4*)(rowp + kt*32 + 4);
  }

  f32x4 acc[4];
  #pragma unroll
  for (int nt = 0; nt < 4; nt++) acc[nt] = (f32x4){0.f, 0.f, 0.f, 0.f};
  #pragma unroll
  for (int kt = 0; kt < 4; kt++) {
    const float4 u = ald[kt*2], w = ald[kt*2+1];
    bf16x8 af;
    af[0] = (short)f2b(u.x); af[1] = (short)f2b(u.y);
    af[2] = (short)f2b(u.z); af[3] = (short)f2b(u.w);
    af[4] = (short)f2b(w.x); af[5] = (short)f2b(w.y);
    af[6] = (short)f2b(w.z); af[7] = (short)f2b(w.w);
    #pragma unroll
    for (int nt = 0; nt < 4; nt++)
      acc[nt] = __builtin_amdgcn_mfma_f32_16x16x32_bf16(wfrag[kt*4+nt], af, acc[nt], 0, 0, 0);
  }

  // score dots: per-lane partial over its 16 features, reduce over g (xor 16,32)
  float t1 = 0.f, t2 = 0.f;
  #pragma unroll
  for (int nt = 0; nt < 4; nt++)
    #pragma unroll
    for (int v = 0; v < 4; v++) {
      t1 = fmaf(acc[nt][v], a1r[nt][v], t1);
      t2 = fmaf(acc[nt][v], a2r[nt][v], t2);
    }
  t1 += __shfl_xor(t1, 16); t1 += __shfl_xor(t1, 32);
  t2 += __shfl_xor(t2, 16); t2 += __shfl_xor(t2, 32);
  if (lane < 16) {
    s1ne[(long)(r0 + lane)*2 + pass] = t1;
    s2ne[(long)(r0 + lane)*2 + pass] = t2;
  }

  // table stores: 4 x uint2 per lane (features g*4..g*4+3 of row r0+c)
  ushort* rowt = hev + (long)(r0 + c)*128 + pass*64 + g*4;
  #pragma unroll
  for (int nt = 0; nt < 4; nt++) {
    uint2 pkv;
    pkv.x = (uint)f2b(acc[nt][0]) | ((uint)f2b(acc[nt][1]) << 16);
    pkv.y = (uint)f2b(acc[nt][2]) | ((uint)f2b(acc[nt][3]) << 16);
    *(uint2*)(rowt + nt*16) = pkv;
  }
}

// K2: one wave = 4 nodes (64 edges). Gather: each load instr fetches FOUR
// 256B rows (uint4/lane, 16 lanes per row) -> 16 loads/group. Weights via
// 2 shuffles + select. Per-node cross-lane combine: shfl_xor(16), (32).
__global__ __launch_bounds__(256) void attn_kernel(
    const uint* __restrict__ hev,   // [NN][64] uints = [NN][128] bf16 (hv | ev)
    const float2* __restrict__ s1ne, const float2* __restrict__ s2ne,
    const int* __restrict__ edges,
    float* __restrict__ outp, double* __restrict__ partials)
{
  const int tid  = threadIdx.x;
  const int wv   = tid >> 6;
  const int lane = tid & 63;
  const int j    = lane >> 4;      // sub-node 0..3
  const int cl   = lane & 15;      // 16-lane column-block index
  double a_qn = 0.0, a_qe = 0.0;
  float* node_out = outp;
  float* edge_out = outp + (long)NN*128;
  const int NG = NN/4;             // 12500 groups
  for (int grp = blockIdx.x*4 + wv; grp < NG; grp += gridDim.x*4) {
    const int i0 = grp*4;
    const int dst = edges[((long)i0*16 + lane)*2 + 1];
    const float2 s1v = s1ne[i0 + j];
    const float2 gsc = s2ne[dst];
    float xn = s1v.x + gsc.x;
    float xe = s1v.y + gsc.y;
    xn = xn > 0.f ? xn : 0.2f*xn;
    xe = xe > 0.f ? xe : 0.2f*xe;
    xn = fminf(fmaxf(xn, -2.f), 2.f);
    xe = fminf(fmaxf(xe, -2.f), 2.f);
    const float an = expf(xn);
    const float ae = expf(xe);
    float sn = an, se = ae;
    #pragma unroll
    for (int off = 1; off < 16; off <<= 1) {
      sn += __shfl_xor(sn, off);
      se += __shfl_xor(se, off);
    }
    const float wn = an / sn;
    const float we = ae / se;
    float rq = wn*wn, re = we*we;
    #pragma unroll
    for (int off = 1; off < 64; off <<= 1) {
      rq += __shfl_xor(rq, off);
      re += __shfl_xor(re, off);
    }
    if (lane == 0) { a_qn += (double)rq; a_qe += (double)re; }

    // own-row first halves
    {
      const uint4 ov = *(const uint4*)(hev + (long)(i0 + j)*64 + cl*4);
      float* ob = ((cl < 8) ? node_out : edge_out) + (long)(i0 + j)*128 + 8*(cl & 7);
      *(float4*)(ob)     = make_float4(b2f(ov.x & 0xffffu), bhi(ov.x),
                                       b2f(ov.y & 0xffffu), bhi(ov.y));
      *(float4*)(ob + 4) = make_float4(b2f(ov.z & 0xffffu), bhi(ov.z),
                                       b2f(ov.w & 0xffffu), bhi(ov.w));
    }

    #pragma unroll
    for (int t = 0; t < 4; t++) {
      float acc[8];
      #pragma unroll
      for (int u = 0; u < 8; u++) acc[u] = 0.f;
      #pragma unroll
      for (int m = 0; m < 4; m++) {
        const int sl    = t*16 + m*4 + j;
        const int d     = __shfl(dst, sl);
        const float w2n = __shfl(wn, sl);
        const float w2e = __shfl(we, sl);
        const float wk  = (cl < 8) ? w2n : w2e;
        const uint4 v = *(const uint4*)(hev + (long)d*64 + cl*4);
        acc[0] = fmaf(wk, b2f(v.x & 0xffffu), acc[0]);
        acc[1] = fmaf(wk, bhi(v.x),           acc[1]);
        acc[2] = fmaf(wk, b2f(v.y & 0xffffu), acc[2]);
        acc[3] = fmaf(wk, bhi(v.y),           acc[3]);
        acc[4] = fmaf(wk, b2f(v.z & 0xffffu), acc[4]);
        acc[5] = fmaf(wk, bhi(v.z),           acc[5]);
        acc[6] = fmaf(wk, b2f(v.w & 0xffffu), acc[6]);
        acc[7] = fmaf(wk, bhi(v.w),           acc[7]);
      }
      #pragma unroll
      for (int u = 0; u < 8; u++) {
        acc[u] += __shfl_xor(acc[u], 16);
        acc[u] += __shfl_xor(acc[u], 32);
      }
      if (lane < 16) {
        float* base = ((cl < 8) ? node_out : edge_out)
                      + (long)(i0 + t)*128 + 64 + 8*(cl & 7);
        *(float4*)(base)     = make_float4(acc[0], acc[1], acc[2], acc[3]);
        *(float4*)(base + 4) = make_float4(acc[4], acc[5], acc[6], acc[7]);
      }
    }
  }
  __shared__ double red[4][2];
  if (lane == 0) { red[wv][0] = a_qn; red[wv][1] = a_qe; }
  __syncthreads();
  if (tid == 0) {
    double t0 = 0, t1 = 0;
    #pragma unroll
    for (int w = 0; w < 4; w++) { t0 += red[w][0]; t1 += red[w][1]; }
    double* p = partials + (long)blockIdx.x*2;
    p[0] = t0; p[1] = t1;
  }
}

// K3: reduce partials -> the two variance scalars (sum of weights is exactly N)
__global__ __launch_bounds__(256) void finalize_kernel(
    const double* __restrict__ partials, int nparts, float* __restrict__ outp)
{
  const int tid = threadIdx.x;
  double l0 = 0, l1 = 0;
  for (int b = tid; b < nparts; b += 256) {
    l0 += partials[b*2+0]; l1 += partials[b*2+1];
  }
  __shared__ double red[256][2];
  red[tid][0] = l0; red[tid][1] = l1;
  __syncthreads();
  for (int s = 128; s > 0; s >>= 1) {
    if (tid < s) {
      red[tid][0] += red[tid+s][0];
      red[tid][1] += red[tid+s][1];
    }
    __syncthreads();
  }
  if (tid == 0) {
    const double E = (double)EE;
    const double S = (double)NN;
    double varn = (red[0][0] - S*S/E) / (E - 1.0);
    double vare = (red[0][1] - S*S/E) / (E - 1.0);
    outp[(long)NN*256 + 0] = (float)varn;
    outp[(long)NN*256 + 1] = (float)vare;
  }
}

extern "C" void kernel_launch(void* const* d_in, const int* in_sizes, int n_in,
                              void* d_out, int out_size, void* d_ws, size_t ws_size,
                              hipStream_t stream)
{
  const float* node_fts = (const float*)d_in[0];
  const float* edge_fts = (const float*)d_in[1];
  const int*   edges    = (const int*)d_in[2];
  const float* W_node   = (const float*)d_in[3];
  const float* W_edge   = (const float*)d_in[4];
  const float* a_node   = (const float*)d_in[5];
  const float* a_edge   = (const float*)d_in[6];

  char* ws = (char*)d_ws;
  ushort* hev = (ushort*)(ws);                       // 12.8 MB interleaved table
  float* s1ne = (float*)(ws + 12800000);
  float* s2ne = (float*)(ws + 13200000);
  double* partials = (double*)(ws + 13600000);
  uint4* wf = (uint4*)(ws + 14000000);               // 32 KB fragment-ordered W
  float* outp = (float*)d_out;

  hipLaunchKernelGGL(prep_kernel, dim3(4, 2), dim3(256), 0, stream,
                     W_node, W_edge, wf);
  hipLaunchKernelGGL(gemm_mfma_kernel, dim3(782, 2), dim3(256), 0, stream,
                     node_fts, edge_fts, wf, a_node, a_edge,
                     hev, s1ne, s2ne);
  const int AB = 3125;
  hipLaunchKernelGGL(attn_kernel, dim3(AB), dim3(256), 0, stream,
                     (const uint*)hev,
                     (const float2*)s1ne, (const float2*)s2ne,
                     edges, outp, partials);
  hipLaunchKernelGGL(finalize_kernel, dim3(1), dim3(256), 0, stream,
                     partials, AB, outp);
}